// Round 3
// baseline (878.400 us; speedup 1.0000x reference)
//
#include <hip/hip_runtime.h>
#include <hip/hip_bf16.h>

// Dims fixed by the problem: B=2, L=2048, H=16, D=64, E=1024.
// MEASURED (round 2): device inputs are FP32 (bf16-read gives NaN; detector flag=0 path ran).
// DEDUCED (round 2): d_out is FP32 (bf16 writes failed with error > max|ref|; packed-pair signature).
#define LOG2E 1.44269504088896340736f

typedef __attribute__((ext_vector_type(8))) short s16x8;   // 8 x bf16 (4 VGPRs) MFMA operand
typedef __attribute__((ext_vector_type(4))) float f32x4;   // MFMA accumulator / fp32 vec load

__device__ inline short f2bf(float f) {
  __hip_bfloat16 h = __float2bfloat16(f);
  union { __hip_bfloat16 h; short s; } u; u.h = h; return u.s;
}

// Load 8 consecutive elements (element offset eoff) as a bf16 fragment.
__device__ inline s16x8 load8(const void* base, size_t eoff, int isf32) {
  if (isf32) {
    const float* p = (const float*)base + eoff;
    f32x4 a = *(const f32x4*)p;
    f32x4 b = *(const f32x4*)(p + 4);
    s16x8 r;
    r[0] = f2bf(a[0]); r[1] = f2bf(a[1]); r[2] = f2bf(a[2]); r[3] = f2bf(a[3]);
    r[4] = f2bf(b[0]); r[5] = f2bf(b[1]); r[6] = f2bf(b[2]); r[7] = f2bf(b[3]);
    return r;
  }
  return *(const s16x8*)((const short*)base + eoff);
}

// flag=1 if net_in is bf16, 0 if float32 (exponent-field census; >17 sigma separation).
__global__ void detect_dtype(const short* __restrict__ net_in, int* __restrict__ flag) {
  int t = threadIdx.x;  // 256 threads
  short s = net_in[2 * t];
  int e = (s >> 7) & 0xFF;
  int pred = (e >= 100 && e <= 150) ? 1 : 0;
  unsigned long long m = __ballot(pred != 0);
  __shared__ int cnt[4];
  if ((t & 63) == 0) cnt[t >> 6] = __popcll(m);
  __syncthreads();
  if (t == 0) flag[0] = (cnt[0] + cnt[1] + cnt[2] + cnt[3] >= 160) ? 1 : 0;
}

// C[M,N] = A[M,K] @ B[N,K]^T  (fp32 acc). A/B bf16 or fp32 per flag; C bf16 or fp32 per outF32.
__global__ __launch_bounds__(256)
void gemm_bt(const void* __restrict__ A, const void* __restrict__ B,
             void* __restrict__ C, int M, int N, int K,
             const int* __restrict__ flag, int aDyn, int bDyn, int outF32) {
  int isbf = *flag;
  int af32 = aDyn && !isbf;
  int bf32 = bDyn && !isbf;
  int wave = threadIdx.x >> 6, lane = threadIdx.x & 63;
  int l16 = lane & 15, quad = lane >> 4;
  int m0 = blockIdx.x * 64 + wave * 16;
  int n0 = blockIdx.y * 64;
  size_t aoff = (size_t)(m0 + l16) * K + quad * 8;
  size_t boff = (size_t)(n0 + l16) * K + quad * 8;
  f32x4 acc[4];
#pragma unroll
  for (int j = 0; j < 4; ++j) acc[j] = (f32x4){0.f, 0.f, 0.f, 0.f};

  if (!af32 && !bf32) {  // pure bf16 fast path
    const short* arow = (const short*)A + aoff;
    const short* brow = (const short*)B + boff;
    for (int k0 = 0; k0 < K; k0 += 32) {
      s16x8 a = *(const s16x8*)(arow + k0);
#pragma unroll
      for (int j = 0; j < 4; ++j) {
        s16x8 b = *(const s16x8*)(brow + (size_t)j * 16 * K + k0);
        acc[j] = __builtin_amdgcn_mfma_f32_16x16x32_bf16(a, b, acc[j], 0, 0, 0);
      }
    }
  } else {               // fp32 operand(s): convert on load
    for (int k0 = 0; k0 < K; k0 += 32) {
      s16x8 a = load8(A, aoff + k0, af32);
#pragma unroll
      for (int j = 0; j < 4; ++j) {
        s16x8 b = load8(B, boff + (size_t)j * 16 * K + k0, bf32);
        acc[j] = __builtin_amdgcn_mfma_f32_16x16x32_bf16(a, b, acc[j], 0, 0, 0);
      }
    }
  }
  if (outF32) {
    float* Cf = (float*)C;
#pragma unroll
    for (int j = 0; j < 4; ++j)
#pragma unroll
      for (int r = 0; r < 4; ++r)
        Cf[(size_t)(m0 + quad * 4 + r) * N + n0 + j * 16 + l16] = acc[j][r];
  } else {
    short* Cs = (short*)C;
#pragma unroll
    for (int j = 0; j < 4; ++j)
#pragma unroll
      for (int r = 0; r < 4; ++r)
        Cs[(size_t)(m0 + quad * 4 + r) * N + n0 + j * 16 + l16] = f2bf(acc[j][r]);
  }
}

// Flash attention, causal. qkv: [4096][3072] bf16 (q|k|v, each 1024 = 16 heads x 64).
// out: [4096][1024] bf16 in (b, t, h*64+d) layout.
__global__ __launch_bounds__(256)
void attn(const short* __restrict__ qkv, short* __restrict__ out) {
  const int L = 2048, E3 = 3072, EO = 1024, D = 64;
  int bh = blockIdx.y;            // 0..31
  int b = bh >> 4, h = bh & 15;
  int q0 = blockIdx.x * 64;
  int wave = threadIdx.x >> 6, lane = threadIdx.x & 63;
  int l16 = lane & 15, quad = lane >> 4;
  int qw = q0 + wave * 16;
  const float SENT = -3.0e38f;    // large-finite mask sentinel (no inf arithmetic)

  __shared__ __align__(16) short Ks[32 * 72];
  __shared__ __align__(16) short Vs[64 * 40];
  __shared__ __align__(16) short Ps[4][16 * 40];

  int rowbase = b * L;
  const short* qptr = qkv + (size_t)(rowbase + qw + l16) * E3 + h * D + quad * 8;
  s16x8 qf0 = *(const s16x8*)(qptr);        // A-frag, k = 0..31
  s16x8 qf1 = *(const s16x8*)(qptr + 32);   // A-frag, k = 32..63

  float m_r[4], l_r[4];
  f32x4 o[4];
#pragma unroll
  for (int r = 0; r < 4; ++r) { m_r[r] = SENT; l_r[r] = 0.f; }
#pragma unroll
  for (int j = 0; j < 4; ++j) o[j] = (f32x4){0.f, 0.f, 0.f, 0.f};

  const float SC = 0.125f * LOG2E;          // exp2-domain logits
  int nkb = q0 / 32 + 2;
  int srow = threadIdx.x & 31, scb = (threadIdx.x >> 5) * 8;

  for (int kb = 0; kb < nkb; ++kb) {
    int key0 = kb * 32;
    __syncthreads();  // previous tile fully consumed
    {
      const short* kp = qkv + (size_t)(rowbase + key0 + srow) * E3 + EO + h * D + scb;
      s16x8 kv = *(const s16x8*)kp;
      *(s16x8*)(&Ks[srow * 72 + scb]) = kv;
      s16x8 vv = *(const s16x8*)(kp + EO);
#pragma unroll
      for (int i = 0; i < 8; ++i) Vs[(scb + i) * 40 + srow] = vv[i];  // transpose
    }
    __syncthreads();
    if (key0 > qw + 15) continue;  // wave fully masked (skip is wave-uniform, after barriers)

    f32x4 sf[2];
#pragma unroll
    for (int n = 0; n < 2; ++n) {
      s16x8 kf0 = *(const s16x8*)(&Ks[(n * 16 + l16) * 72 + quad * 8]);
      s16x8 kf1 = *(const s16x8*)(&Ks[(n * 16 + l16) * 72 + 32 + quad * 8]);
      f32x4 t = (f32x4){0.f, 0.f, 0.f, 0.f};
      t = __builtin_amdgcn_mfma_f32_16x16x32_bf16(qf0, kf0, t, 0, 0, 0);
      t = __builtin_amdgcn_mfma_f32_16x16x32_bf16(qf1, kf1, t, 0, 0, 0);
      sf[n] = t;
    }

    float p0[4], p1[4], alpha[4];
#pragma unroll
    for (int r = 0; r < 4; ++r) {
      int qrow = qw + quad * 4 + r;
      float s0 = (key0 + l16      <= qrow) ? sf[0][r] * SC : SENT;
      float s1 = (key0 + 16 + l16 <= qrow) ? sf[1][r] * SC : SENT;
      float rx = fmaxf(s0, s1);
      rx = fmaxf(rx, __shfl_xor(rx, 1));
      rx = fmaxf(rx, __shfl_xor(rx, 2));
      rx = fmaxf(rx, __shfl_xor(rx, 4));
      rx = fmaxf(rx, __shfl_xor(rx, 8));
      float mn = fmaxf(m_r[r], rx);          // finite from kb=0 on
      alpha[r] = exp2f(m_r[r] - mn);
      p0[r] = exp2f(s0 - mn);
      p1[r] = exp2f(s1 - mn);
      float rs = p0[r] + p1[r];
      rs += __shfl_xor(rs, 1);
      rs += __shfl_xor(rs, 2);
      rs += __shfl_xor(rs, 4);
      rs += __shfl_xor(rs, 8);
      l_r[r] = l_r[r] * alpha[r] + rs;
      m_r[r] = mn;
    }
#pragma unroll
    for (int j = 0; j < 4; ++j)
#pragma unroll
      for (int r = 0; r < 4; ++r) o[j][r] *= alpha[r];

    // P: C-layout -> per-wave LDS scratch -> A-layout
    short* pw = (short*)Ps[wave];
#pragma unroll
    for (int r = 0; r < 4; ++r) {
      pw[(quad * 4 + r) * 40 + l16]      = f2bf(p0[r]);
      pw[(quad * 4 + r) * 40 + 16 + l16] = f2bf(p1[r]);
    }
    asm volatile("s_waitcnt lgkmcnt(0)" ::: "memory");  // cross-lane RAW through LDS
    s16x8 pf = *(const s16x8*)(&pw[l16 * 40 + quad * 8]);

#pragma unroll
    for (int j = 0; j < 4; ++j) {
      s16x8 vf = *(const s16x8*)(&Vs[(j * 16 + l16) * 40 + quad * 8]);
      o[j] = __builtin_amdgcn_mfma_f32_16x16x32_bf16(pf, vf, o[j], 0, 0, 0);
    }
  }

#pragma unroll
  for (int r = 0; r < 4; ++r) {
    float inv = 1.f / l_r[r];
    int orow = rowbase + qw + quad * 4 + r;
#pragma unroll
    for (int j = 0; j < 4; ++j)
      out[(size_t)orow * EO + h * D + j * 16 + l16] = f2bf(o[j][r] * inv);
  }
}

extern "C" void kernel_launch(void* const* d_in, const int* in_sizes, int n_in,
                              void* d_out, int out_size, void* d_ws, size_t ws_size,
                              hipStream_t stream) {
  const void* net_in = d_in[0];   // [2,2048,1024] fp32 (measured; detector keeps us robust)
  const void* W_qkv  = d_in[1];   // [3072,1024]
  const void* W_out  = d_in[2];   // [1024,1024]

  int*   flag  = (int*)d_ws;                          // 4 B (+pad to 256)
  short* qkv   = (short*)((char*)d_ws + 256);         // 4096*3072 bf16 = 24 MB
  short* attno = qkv + (size_t)4096 * 3072;           // 4096*1024 bf16 =  8 MB

  detect_dtype<<<1, 256, 0, stream>>>((const short*)net_in, flag);
  // 1) qkv = net_in @ W_qkv^T   (M=4096, N=3072, K=1024), bf16 out to workspace
  gemm_bt<<<dim3(64, 48), 256, 0, stream>>>(net_in, W_qkv, qkv, 4096, 3072, 1024, flag, 1, 1, 0);
  // 2) causal flash attention -> (b, t, e) bf16
  attn<<<dim3(32, 32), 256, 0, stream>>>(qkv, attno);
  // 3) out = attn_out @ W_out^T (M=4096, N=1024, K=1024), FP32 out to d_out
  gemm_bt<<<dim3(64, 16), 256, 0, stream>>>(attno, W_out, d_out, 4096, 1024, 1024, flag, 0, 1, 1);
}

// Round 4
// 324.880 us; speedup vs baseline: 2.7038x; 2.7038x over previous
//
#include <hip/hip_runtime.h>
#include <hip/hip_bf16.h>

// Dims fixed by the problem: B=2, L=2048, H=16, D=64, E=1024.
// MEASURED: device inputs fp32, d_out fp32 (rounds 2-3). bf16 internal compute passes
// with absmax 0.0156 vs threshold 0.0766 (round 3).
#define LOG2E 1.44269504088896340736f

typedef __attribute__((ext_vector_type(8))) short s16x8;   // 8 x bf16 MFMA operand
typedef __attribute__((ext_vector_type(4))) short s16x4;
typedef __attribute__((ext_vector_type(4))) float f32x4;   // MFMA accumulator

__device__ inline short f2bf(float f) {
  __hip_bfloat16 h = __float2bfloat16(f);
  union { __hip_bfloat16 h; short s; } u; u.h = h; return u.s;
}

// async global->LDS, 16B per lane. LDS placement is wave-uniform base + lane*16.
__device__ inline void gl_lds16(const void* g, void* l) {
  __builtin_amdgcn_global_load_lds(
      (const __attribute__((address_space(1))) void*)g,
      (__attribute__((address_space(3))) void*)l, 16, 0, 0);
}

__global__ __launch_bounds__(256)
void cvt_f32_bf16(const float* __restrict__ src, short* __restrict__ dst, int n4) {
  int i = blockIdx.x * 256 + threadIdx.x;
  if (i < n4) {
    f32x4 v = ((const f32x4*)src)[i];
    s16x4 o;
    o[0] = f2bf(v[0]); o[1] = f2bf(v[1]); o[2] = f2bf(v[2]); o[3] = f2bf(v[3]);
    ((s16x4*)dst)[i] = o;
  }
}

// C[M,N] = A[M,K] @ B[N,K]^T.  m97-style 128x128 tile, BK=32, 4 waves (2x2), acc[4][4].
// AF32: A is fp32 (staged raw via global_load_lds with XOR-swizzled source permutation,
//       converted to bf16 at fragment read). Else A is bf16, row stride lda.
// OUTF32: C fp32 else bf16. B is bf16 [N][K], row stride K.
template<int AF32, int OUTF32>
__global__ __launch_bounds__(256)
void gemm128(const void* __restrict__ Ap, int lda,
             const short* __restrict__ B,
             void* __restrict__ Cp, int ldc, int K) {
  int m0 = blockIdx.x * 128;
  int n0 = blockIdx.y * 128;
  int t = threadIdx.x;
  int w = t >> 6, lane = t & 63;
  int l16 = lane & 15, quad = lane >> 4;
  int wm = w >> 1, wn = w & 1;   // wave covers rows wm*64.., cols wn*64..

  __shared__ __align__(16) short Bs[128 * 32];                    // 8 KB
  __shared__ __align__(16) short AsH[AF32 ? 1 : 128 * 32];        // 8 KB (bf16 A)
  __shared__ __align__(16) float AsF[AF32 ? 128 * 32 : 1];        // 16 KB (fp32 A)

  // --- staging source addresses (per thread) ---
  // B tile: cell = 16B = 8 bf16. slot s = r*256 + t -> row = s>>2, c = s&3.
  const short* bsrc = B + (size_t)(n0 + (t >> 2)) * K + (t & 3) * 8;
  // A bf16: same mapping with stride lda.
  const short* ahsrc = AF32 ? (const short*)nullptr
                            : (const short*)Ap + (size_t)(m0 + (t >> 2)) * lda + (t & 3) * 8;
  // A fp32: cell = 16B = 4 floats, 8 cells/row. LDS slot s = r*256 + t holds cell
  // (R = r*32 + (t>>3), c4 = (t&7) ^ (R&7)); note (r*32)&7 == 0 so c4 is r-independent.
  int aR  = t >> 3;
  int ac4 = (t & 7) ^ (aR & 7);
  const float* afsrc = AF32 ? (const float*)Ap + (size_t)(m0 + aR) * lda + ac4 * 4
                            : (const float*)nullptr;

  f32x4 acc[4][4];
#pragma unroll
  for (int i = 0; i < 4; ++i)
#pragma unroll
    for (int j = 0; j < 4; ++j) acc[i][j] = (f32x4){0.f, 0.f, 0.f, 0.f};

  for (int k0 = 0; k0 < K; k0 += 32) {
    __syncthreads();   // previous tile fully consumed
    if (AF32) {
#pragma unroll
      for (int r = 0; r < 4; ++r)
        gl_lds16(afsrc + k0 + (size_t)r * 32 * lda, (char*)AsF + r * 4096 + w * 1024);
    } else {
#pragma unroll
      for (int r = 0; r < 2; ++r)
        gl_lds16(ahsrc + k0 + (size_t)r * 64 * lda, (char*)AsH + r * 4096 + w * 1024);
    }
#pragma unroll
    for (int r = 0; r < 2; ++r)
      gl_lds16(bsrc + k0 + (size_t)r * 64 * K, (char*)Bs + r * 4096 + w * 1024);
    __syncthreads();   // barrier drains vmcnt -> staged data visible

    s16x8 af[4], bf[4];
#pragma unroll
    for (int i = 0; i < 4; ++i) {
      int row = wm * 64 + i * 16 + l16;
      if (AF32) {
        int x = row & 7;
        // fragment floats k=quad*8..+7 live in swizzled slots (cells c4=2q, 2q+1)
        const f32x4 lo = *(const f32x4*)(AsF + (size_t)(row * 8 + ((quad * 2) ^ x)) * 4);
        const f32x4 hi = *(const f32x4*)(AsF + (size_t)(row * 8 + ((quad * 2 + 1) ^ x)) * 4);
        s16x8 a;
        a[0] = f2bf(lo[0]); a[1] = f2bf(lo[1]); a[2] = f2bf(lo[2]); a[3] = f2bf(lo[3]);
        a[4] = f2bf(hi[0]); a[5] = f2bf(hi[1]); a[6] = f2bf(hi[2]); a[7] = f2bf(hi[3]);
        af[i] = a;
      } else {
        af[i] = *(const s16x8*)(AsH + row * 32 + quad * 8);
      }
      bf[i] = *(const s16x8*)(Bs + (wn * 64 + i * 16 + l16) * 32 + quad * 8);
    }
#pragma unroll
    for (int i = 0; i < 4; ++i)
#pragma unroll
      for (int j = 0; j < 4; ++j)
        acc[i][j] = __builtin_amdgcn_mfma_f32_16x16x32_bf16(af[i], bf[j], acc[i][j], 0, 0, 0);
  }

#pragma unroll
  for (int i = 0; i < 4; ++i)
#pragma unroll
    for (int j = 0; j < 4; ++j)
#pragma unroll
      for (int rr = 0; rr < 4; ++rr) {
        size_t row = m0 + wm * 64 + i * 16 + quad * 4 + rr;
        size_t col = n0 + wn * 64 + j * 16 + l16;
        if (OUTF32) ((float*)Cp)[row * ldc + col] = acc[i][j][rr];
        else        ((short*)Cp)[row * ldc + col] = f2bf(acc[i][j][rr]);
      }
}

// Flash attention, causal. qkv: [4096][3072] bf16 (q|k|v, each 16 heads x 64).
// Output written IN-PLACE into the Q region (cols h*64..h*64+63) — block (q0,h) is the
// sole reader and sole writer of that region (Q read into regs before the loop).
__global__ __launch_bounds__(256)
void attn(short* __restrict__ qkv) {
  const int L = 2048, E3 = 3072, EO = 1024, D = 64;
  int bh = blockIdx.y;            // 0..31
  int b = bh >> 4, h = bh & 15;
  int q0 = blockIdx.x * 64;
  int wave = threadIdx.x >> 6, lane = threadIdx.x & 63;
  int l16 = lane & 15, quad = lane >> 4;
  int qw = q0 + wave * 16;
  const float SENT = -3.0e38f;

  __shared__ __align__(16) short Ks[32 * 72];
  __shared__ __align__(16) short Vs[64 * 40];
  __shared__ __align__(16) short Ps[4][16 * 40];

  int rowbase = b * L;
  const short* qptr = qkv + (size_t)(rowbase + qw + l16) * E3 + h * D + quad * 8;
  s16x8 qf0 = *(const s16x8*)(qptr);
  s16x8 qf1 = *(const s16x8*)(qptr + 32);

  float m_r[4], l_r[4];
  f32x4 o[4];
#pragma unroll
  for (int r = 0; r < 4; ++r) { m_r[r] = SENT; l_r[r] = 0.f; }
#pragma unroll
  for (int j = 0; j < 4; ++j) o[j] = (f32x4){0.f, 0.f, 0.f, 0.f};

  const float SC = 0.125f * LOG2E;
  int nkb = q0 / 32 + 2;
  int srow = threadIdx.x & 31, scb = (threadIdx.x >> 5) * 8;

  for (int kb = 0; kb < nkb; ++kb) {
    int key0 = kb * 32;
    __syncthreads();
    {
      const short* kp = qkv + (size_t)(rowbase + key0 + srow) * E3 + EO + h * D + scb;
      s16x8 kv = *(const s16x8*)kp;
      *(s16x8*)(&Ks[srow * 72 + scb]) = kv;
      s16x8 vv = *(const s16x8*)(kp + EO);
#pragma unroll
      for (int i = 0; i < 8; ++i) Vs[(scb + i) * 40 + srow] = vv[i];
    }
    __syncthreads();
    if (key0 > qw + 15) continue;

    f32x4 sf[2];
#pragma unroll
    for (int n = 0; n < 2; ++n) {
      s16x8 kf0 = *(const s16x8*)(&Ks[(n * 16 + l16) * 72 + quad * 8]);
      s16x8 kf1 = *(const s16x8*)(&Ks[(n * 16 + l16) * 72 + 32 + quad * 8]);
      f32x4 tacc = (f32x4){0.f, 0.f, 0.f, 0.f};
      tacc = __builtin_amdgcn_mfma_f32_16x16x32_bf16(qf0, kf0, tacc, 0, 0, 0);
      tacc = __builtin_amdgcn_mfma_f32_16x16x32_bf16(qf1, kf1, tacc, 0, 0, 0);
      sf[n] = tacc;
    }

    float p0[4], p1[4], alpha[4];
#pragma unroll
    for (int r = 0; r < 4; ++r) {
      int qrow = qw + quad * 4 + r;
      float s0 = (key0 + l16      <= qrow) ? sf[0][r] * SC : SENT;
      float s1 = (key0 + 16 + l16 <= qrow) ? sf[1][r] * SC : SENT;
      float rx = fmaxf(s0, s1);
      rx = fmaxf(rx, __shfl_xor(rx, 1));
      rx = fmaxf(rx, __shfl_xor(rx, 2));
      rx = fmaxf(rx, __shfl_xor(rx, 4));
      rx = fmaxf(rx, __shfl_xor(rx, 8));
      float mn = fmaxf(m_r[r], rx);
      alpha[r] = exp2f(m_r[r] - mn);
      p0[r] = exp2f(s0 - mn);
      p1[r] = exp2f(s1 - mn);
      float rs = p0[r] + p1[r];
      rs += __shfl_xor(rs, 1);
      rs += __shfl_xor(rs, 2);
      rs += __shfl_xor(rs, 4);
      rs += __shfl_xor(rs, 8);
      l_r[r] = l_r[r] * alpha[r] + rs;
      m_r[r] = mn;
    }
#pragma unroll
    for (int j = 0; j < 4; ++j)
#pragma unroll
      for (int r = 0; r < 4; ++r) o[j][r] *= alpha[r];

    short* pw = (short*)Ps[wave];
#pragma unroll
    for (int r = 0; r < 4; ++r) {
      pw[(quad * 4 + r) * 40 + l16]      = f2bf(p0[r]);
      pw[(quad * 4 + r) * 40 + 16 + l16] = f2bf(p1[r]);
    }
    asm volatile("s_waitcnt lgkmcnt(0)" ::: "memory");
    s16x8 pf = *(const s16x8*)(&pw[l16 * 40 + quad * 8]);

#pragma unroll
    for (int j = 0; j < 4; ++j) {
      s16x8 vf = *(const s16x8*)(&Vs[(j * 16 + l16) * 40 + quad * 8]);
      o[j] = __builtin_amdgcn_mfma_f32_16x16x32_bf16(pf, vf, o[j], 0, 0, 0);
    }
  }

  // epilogue: write into own Q region (row stride E3)
#pragma unroll
  for (int r = 0; r < 4; ++r) {
    float inv = 1.f / l_r[r];
    int orow = rowbase + qw + quad * 4 + r;
#pragma unroll
    for (int j = 0; j < 4; ++j)
      qkv[(size_t)orow * E3 + h * D + j * 16 + l16] = f2bf(o[j][r] * inv);
  }
}

extern "C" void kernel_launch(void* const* d_in, const int* in_sizes, int n_in,
                              void* d_out, int out_size, void* d_ws, size_t ws_size,
                              hipStream_t stream) {
  const float* net_in = (const float*)d_in[0];   // [4096,1024] fp32
  const float* W_qkv  = (const float*)d_in[1];   // [3072,1024] fp32
  const float* W_out  = (const float*)d_in[2];   // [1024,1024] fp32

  // ws layout (32 MB total): Wqkvb 6 MB | Woutb 2 MB | qkv 24 MB
  short* Wqkvb = (short*)d_ws;
  short* Woutb = Wqkvb + (size_t)3072 * 1024;
  short* qkv   = Woutb + (size_t)1024 * 1024;

  cvt_f32_bf16<<<3072, 256, 0, stream>>>(W_qkv, Wqkvb, 3072 * 1024 / 4);
  cvt_f32_bf16<<<1024, 256, 0, stream>>>(W_out, Woutb, 1024 * 1024 / 4);

  // 1) qkv = net_in @ W_qkv^T  (A fp32 direct, C bf16, ldc 3072)
  gemm128<1, 0><<<dim3(32, 24), 256, 0, stream>>>(net_in, 1024, Wqkvb, qkv, 3072, 1024);
  // 2) causal flash attention, output in-place into Q region of qkv
  attn<<<dim3(32, 32), 256, 0, stream>>>(qkv);
  // 3) out = attn_out @ W_out^T  (A bf16 = qkv Q-region lda 3072, C fp32)
  gemm128<0, 1><<<dim3(32, 8), 256, 0, stream>>>(qkv, 3072, Woutb, d_out, 1024, 1024);
}

// Round 5
// 274.870 us; speedup vs baseline: 3.1957x; 1.1819x over previous
//
#include <hip/hip_runtime.h>
#include <hip/hip_bf16.h>

// Dims fixed by the problem: B=2, L=2048, H=16, D=64, E=1024.
// MEASURED: inputs fp32, d_out fp32; bf16 internal compute absmax 0.0156 vs thr 0.0766.
#define LOG2E 1.44269504088896340736f

typedef __attribute__((ext_vector_type(8))) short s16x8;   // 8 x bf16 MFMA operand
typedef __attribute__((ext_vector_type(4))) short s16x4;
typedef __attribute__((ext_vector_type(4))) float f32x4;   // MFMA accumulator

__device__ inline short f2bf(float f) {
  __hip_bfloat16 h = __float2bfloat16(f);
  union { __hip_bfloat16 h; short s; } u; u.h = h; return u.s;
}

// async global->LDS, 16B per lane. LDS placement is wave-uniform base + lane*16.
__device__ inline void gl_lds16(const void* g, void* l) {
  __builtin_amdgcn_global_load_lds(
      (const __attribute__((address_space(1))) void*)g,
      (__attribute__((address_space(3))) void*)l, 16, 0, 0);
}

__global__ __launch_bounds__(256)
void cvt_f32_bf16(const float* __restrict__ src, short* __restrict__ dst, int n4) {
  int i = blockIdx.x * 256 + threadIdx.x;
  if (i < n4) {
    f32x4 v = ((const f32x4*)src)[i];
    s16x4 o;
    o[0] = f2bf(v[0]); o[1] = f2bf(v[1]); o[2] = f2bf(v[2]); o[3] = f2bf(v[3]);
    ((s16x4*)dst)[i] = o;
  }
}

// C[M,N] = A[M,K] @ B[N,K]^T.  m97-style 128x128 tile, BK=32, 4 waves (2x2), acc[4][4].
template<int AF32, int OUTF32>
__global__ __launch_bounds__(256)
void gemm128(const void* __restrict__ Ap, int lda,
             const short* __restrict__ B,
             void* __restrict__ Cp, int ldc, int K) {
  int m0 = blockIdx.x * 128;
  int n0 = blockIdx.y * 128;
  int t = threadIdx.x;
  int w = t >> 6, lane = t & 63;
  int l16 = lane & 15, quad = lane >> 4;
  int wm = w >> 1, wn = w & 1;

  __shared__ __align__(16) short Bs[128 * 32];                    // 8 KB
  __shared__ __align__(16) short AsH[AF32 ? 1 : 128 * 32];        // 8 KB (bf16 A)
  __shared__ __align__(16) float AsF[AF32 ? 128 * 32 : 1];        // 16 KB (fp32 A)

  const short* bsrc = B + (size_t)(n0 + (t >> 2)) * K + (t & 3) * 8;
  const short* ahsrc = AF32 ? (const short*)nullptr
                            : (const short*)Ap + (size_t)(m0 + (t >> 2)) * lda + (t & 3) * 8;
  int aR  = t >> 3;
  int ac4 = (t & 7) ^ (aR & 7);
  const float* afsrc = AF32 ? (const float*)Ap + (size_t)(m0 + aR) * lda + ac4 * 4
                            : (const float*)nullptr;

  f32x4 acc[4][4];
#pragma unroll
  for (int i = 0; i < 4; ++i)
#pragma unroll
    for (int j = 0; j < 4; ++j) acc[i][j] = (f32x4){0.f, 0.f, 0.f, 0.f};

  for (int k0 = 0; k0 < K; k0 += 32) {
    __syncthreads();
    if (AF32) {
#pragma unroll
      for (int r = 0; r < 4; ++r)
        gl_lds16(afsrc + k0 + (size_t)r * 32 * lda, (char*)AsF + r * 4096 + w * 1024);
    } else {
#pragma unroll
      for (int r = 0; r < 2; ++r)
        gl_lds16(ahsrc + k0 + (size_t)r * 64 * lda, (char*)AsH + r * 4096 + w * 1024);
    }
#pragma unroll
    for (int r = 0; r < 2; ++r)
      gl_lds16(bsrc + k0 + (size_t)r * 64 * K, (char*)Bs + r * 4096 + w * 1024);
    __syncthreads();

    s16x8 af[4], bf[4];
#pragma unroll
    for (int i = 0; i < 4; ++i) {
      int row = wm * 64 + i * 16 + l16;
      if (AF32) {
        int x = row & 7;
        const f32x4 lo = *(const f32x4*)(AsF + (size_t)(row * 8 + ((quad * 2) ^ x)) * 4);
        const f32x4 hi = *(const f32x4*)(AsF + (size_t)(row * 8 + ((quad * 2 + 1) ^ x)) * 4);
        s16x8 a;
        a[0] = f2bf(lo[0]); a[1] = f2bf(lo[1]); a[2] = f2bf(lo[2]); a[3] = f2bf(lo[3]);
        a[4] = f2bf(hi[0]); a[5] = f2bf(hi[1]); a[6] = f2bf(hi[2]); a[7] = f2bf(hi[3]);
        af[i] = a;
      } else {
        af[i] = *(const s16x8*)(AsH + row * 32 + quad * 8);
      }
      bf[i] = *(const s16x8*)(Bs + (wn * 64 + i * 16 + l16) * 32 + quad * 8);
    }
#pragma unroll
    for (int i = 0; i < 4; ++i)
#pragma unroll
      for (int j = 0; j < 4; ++j)
        acc[i][j] = __builtin_amdgcn_mfma_f32_16x16x32_bf16(af[i], bf[j], acc[i][j], 0, 0, 0);
  }

#pragma unroll
  for (int i = 0; i < 4; ++i)
#pragma unroll
    for (int j = 0; j < 4; ++j)
#pragma unroll
      for (int rr = 0; rr < 4; ++rr) {
        size_t row = m0 + wm * 64 + i * 16 + quad * 4 + rr;
        size_t col = n0 + wn * 64 + j * 16 + l16;
        if (OUTF32) ((float*)Cp)[row * ldc + col] = acc[i][j][rr];
        else        ((short*)Cp)[row * ldc + col] = f2bf(acc[i][j][rr]);
      }
}

// Flash attention, causal, transposed-softmax formulation.
// S^T = K.Q^T (per-lane q = l16, keys in regs) -> in-register softmax reductions
// (2 shfl per 64-key tile) -> P^T via b64 LDS write / b128 B-frag read -> O^T = V^T.P^T.
// Output written in-place into the Q region of qkv (block owns rows [q0,q0+64) x head h).
__global__ __launch_bounds__(256)
void attn(short* __restrict__ qkv) {
  const int L = 2048, E3 = 3072, EO = 1024;
  int bh = blockIdx.y, b = bh >> 4, h = bh & 15;
  int q0 = (int)(gridDim.x - 1 - blockIdx.x) * 64;   // heavy blocks first
  int t = threadIdx.x;
  int wave = t >> 6, lane = t & 63;
  int l16 = lane & 15, quad = lane >> 4;
  int qw = q0 + wave * 16;
  const float SENT = -3.0e38f;
  const float SC = 0.125f * LOG2E;

  __shared__ __align__(16) short Ks[2][64][32];   // [dim chunk][key][dim%32]  8 KB
  __shared__ __align__(16) short Vt[2][64][32];   // [key chunk][dim][key%32]  8 KB
  __shared__ __align__(16) short Pw[4][16][72];   // per-wave P^T [q][key+pad] 9.2 KB

  int rowbase = b * L;
  // Q B-frags (lane l16 = q row), pre-scaled by SC (exp2 domain)
  const short* qp = qkv + (size_t)(rowbase + qw + l16) * E3 + h * 64 + quad * 8;
  s16x8 qf[2];
#pragma unroll
  for (int c = 0; c < 2; ++c) {
    s16x8 raw = *(const s16x8*)(qp + c * 32);
#pragma unroll
    for (int j = 0; j < 8; ++j) {
      union { float f; int i; } u; u.i = ((int)(unsigned short)raw[j]) << 16;
      raw[j] = f2bf(u.f * SC);
    }
    qf[c] = raw;
  }

  // staging source addresses
  const short* ksrc = qkv + (size_t)(rowbase + (t >> 2)) * E3 + EO     + h * 64 + (t & 3) * 8;
  const short* vsrc = qkv + (size_t)(rowbase + (t >> 2)) * E3 + 2 * EO + h * 64 + (t & 3) * 16;
  int vkc = (t >> 2) >> 5, vko = (t >> 2) & 31, vd0 = (t & 3) * 16;

  float m_s = SENT, l_s = 0.f;
  f32x4 o[4];
#pragma unroll
  for (int j = 0; j < 4; ++j) o[j] = (f32x4){0.f, 0.f, 0.f, 0.f};

  int nkb = q0 / 64 + 1;
  for (int kb = 0; kb < nkb; ++kb) {
    size_t koff = (size_t)(kb * 64) * E3;
    __syncthreads();   // previous tile fully consumed
    gl_lds16(ksrc + koff,      (char*)Ks + wave * 1024);          // K dims 0..31
    gl_lds16(ksrc + koff + 32, (char*)Ks + 4096 + wave * 1024);   // K dims 32..63
    {
      s16x8 v0 = *(const s16x8*)(vsrc + koff);
      s16x8 v1 = *(const s16x8*)(vsrc + koff + 8);
#pragma unroll
      for (int i = 0; i < 8; ++i) {
        int ii = i ^ (t & 1);
        Vt[vkc][vd0 + ii][vko]     = v0[ii];
        Vt[vkc][vd0 + 8 + ii][vko] = v1[ii];
      }
    }
    __syncthreads();   // staged data visible

    int mtile = (qw - kb * 64) >> 4;   // >=4: all subtiles full (every tile but the last)

    // S^T per 16-key subtile: C row = key offset (quad*4+r), col = q (l16)
    f32x4 sf[4];
#pragma unroll
    for (int st = 0; st < 4; ++st) {
      if (st <= mtile) {
        s16x8 kf0 = *(const s16x8*)(&Ks[0][st * 16 + l16][quad * 8]);
        s16x8 kf1 = *(const s16x8*)(&Ks[1][st * 16 + l16][quad * 8]);
        f32x4 tt = (f32x4){0.f, 0.f, 0.f, 0.f};
        tt = __builtin_amdgcn_mfma_f32_16x16x32_bf16(kf0, qf[0], tt, 0, 0, 0);
        tt = __builtin_amdgcn_mfma_f32_16x16x32_bf16(kf1, qf[1], tt, 0, 0, 0);
        sf[st] = tt;
      }
    }
    if (mtile < 4) {   // last tile only: diagonal mask + empty subtiles
#pragma unroll
      for (int st = 0; st < 4; ++st) {
        if (st == mtile) {
#pragma unroll
          for (int r = 0; r < 4; ++r)
            if (quad * 4 + r > l16) sf[st][r] = SENT;   // fixed causal pattern
        } else if (st > mtile) {
          sf[st] = (f32x4){SENT, SENT, SENT, SENT};
        }
      }
    }

    // online softmax: in-register reduce + 2 shfl
    float rx = SENT;
#pragma unroll
    for (int st = 0; st < 4; ++st)
#pragma unroll
      for (int r = 0; r < 4; ++r) rx = fmaxf(rx, sf[st][r]);
    rx = fmaxf(rx, __shfl_xor(rx, 16));
    rx = fmaxf(rx, __shfl_xor(rx, 32));
    float mn = fmaxf(m_s, rx);
    float alpha = exp2f(m_s - mn);
    float rs = 0.f;
#pragma unroll
    for (int st = 0; st < 4; ++st)
#pragma unroll
      for (int r = 0; r < 4; ++r) {
        float p = exp2f(sf[st][r] - mn);
        sf[st][r] = p; rs += p;
      }
    rs += __shfl_xor(rs, 16);
    rs += __shfl_xor(rs, 32);
    l_s = l_s * alpha + rs;
    m_s = mn;
#pragma unroll
    for (int j = 0; j < 4; ++j)
#pragma unroll
      for (int r = 0; r < 4; ++r) o[j][r] *= alpha;

    // P^T -> per-wave LDS (b64 per subtile), read back as PV B-frags
#pragma unroll
    for (int st = 0; st < 4; ++st) {
      s16x4 pb;
#pragma unroll
      for (int r = 0; r < 4; ++r) pb[r] = f2bf(sf[st][r]);
      *(s16x4*)(&Pw[wave][l16][st * 16 + quad * 4]) = pb;
    }
    asm volatile("s_waitcnt lgkmcnt(0)" ::: "memory");
#pragma unroll
    for (int kc = 0; kc < 2; ++kc) {
      s16x8 pf = *(const s16x8*)(&Pw[wave][l16][kc * 32 + quad * 8]);
#pragma unroll
      for (int j = 0; j < 4; ++j) {
        s16x8 vf = *(const s16x8*)(&Vt[kc][j * 16 + l16][quad * 8]);
        o[j] = __builtin_amdgcn_mfma_f32_16x16x32_bf16(vf, pf, o[j], 0, 0, 0);
      }
    }
  }

  // epilogue: O^T -> out rows (q = l16), b64 stores into own Q region
  float inv = 1.f / l_s;
  size_t obase = (size_t)(rowbase + qw + l16) * E3 + h * 64;
#pragma unroll
  for (int j = 0; j < 4; ++j) {
    s16x4 ob;
#pragma unroll
    for (int r = 0; r < 4; ++r) ob[r] = f2bf(o[j][r] * inv);
    *(s16x4*)(qkv + obase + j * 16 + quad * 4) = ob;
  }
}

extern "C" void kernel_launch(void* const* d_in, const int* in_sizes, int n_in,
                              void* d_out, int out_size, void* d_ws, size_t ws_size,
                              hipStream_t stream) {
  const float* net_in = (const float*)d_in[0];   // [4096,1024] fp32
  const float* W_qkv  = (const float*)d_in[1];   // [3072,1024] fp32
  const float* W_out  = (const float*)d_in[2];   // [1024,1024] fp32

  short* Wqkvb = (short*)d_ws;                        // 6 MB
  short* Woutb = Wqkvb + (size_t)3072 * 1024;         // 2 MB
  short* qkv   = Woutb + (size_t)1024 * 1024;         // 24 MB

  cvt_f32_bf16<<<3072, 256, 0, stream>>>(W_qkv, Wqkvb, 3072 * 1024 / 4);
  cvt_f32_bf16<<<1024, 256, 0, stream>>>(W_out, Woutb, 1024 * 1024 / 4);

  gemm128<1, 0><<<dim3(32, 24), 256, 0, stream>>>(net_in, 1024, Wqkvb, qkv, 3072, 1024);
  attn<<<dim3(32, 32), 256, 0, stream>>>(qkv);
  gemm128<0, 1><<<dim3(32, 8), 256, 0, stream>>>(qkv, 3072, Woutb, d_out, 1024, 1024);
}

// Round 7
// 260.186 us; speedup vs baseline: 3.3760x; 1.0564x over previous
//
#include <hip/hip_runtime.h>
#include <hip/hip_bf16.h>

// Dims fixed by the problem: B=2, L=2048, H=16, D=64, E=1024.
// MEASURED: inputs fp32, d_out fp32; bf16 internal compute absmax 0.0156 vs thr 0.0766.
// R6 BUG (fixed): Pw stride must be >=64 shorts (64-key P^T rows); 40 overflowed.
#define LOG2E 1.44269504088896340736f

typedef __attribute__((ext_vector_type(8))) short s16x8;   // 8 x bf16 MFMA operand
typedef __attribute__((ext_vector_type(4))) short s16x4;
typedef __attribute__((ext_vector_type(4))) float f32x4;   // MFMA accumulator

__device__ inline short f2bf(float f) {
  __hip_bfloat16 h = __float2bfloat16(f);
  union { __hip_bfloat16 h; short s; } u; u.h = h; return u.s;
}

// async global->LDS, 16B per lane. LDS placement is wave-uniform base + lane*16.
__device__ inline void gl_lds16(const void* g, void* l) {
  __builtin_amdgcn_global_load_lds(
      (const __attribute__((address_space(1))) void*)g,
      (__attribute__((address_space(3))) void*)l, 16, 0, 0);
}

__global__ __launch_bounds__(256)
void cvt_f32_bf16(const float* __restrict__ src, short* __restrict__ dst, int n4) {
  int i = blockIdx.x * 256 + threadIdx.x;
  if (i < n4) {
    f32x4 v = ((const f32x4*)src)[i];
    s16x4 o;
    o[0] = f2bf(v[0]); o[1] = f2bf(v[1]); o[2] = f2bf(v[2]); o[3] = f2bf(v[3]);
    ((s16x4*)dst)[i] = o;
  }
}

// C[M,N] = A[M,K] @ B[N,K]^T.  m97-style 128x128 tile, BK=32, 4 waves (2x2), acc[4][4].
template<int AF32, int OUTF32>
__global__ __launch_bounds__(256)
void gemm128(const void* __restrict__ Ap, int lda,
             const short* __restrict__ B,
             void* __restrict__ Cp, int ldc, int K) {
  int m0 = blockIdx.x * 128;
  int n0 = blockIdx.y * 128;
  int t = threadIdx.x;
  int w = t >> 6, lane = t & 63;
  int l16 = lane & 15, quad = lane >> 4;
  int wm = w >> 1, wn = w & 1;

  __shared__ __align__(16) short Bs[128 * 32];                    // 8 KB
  __shared__ __align__(16) short AsH[AF32 ? 1 : 128 * 32];        // 8 KB (bf16 A)
  __shared__ __align__(16) float AsF[AF32 ? 128 * 32 : 1];        // 16 KB (fp32 A)

  const short* bsrc = B + (size_t)(n0 + (t >> 2)) * K + (t & 3) * 8;
  const short* ahsrc = AF32 ? (const short*)nullptr
                            : (const short*)Ap + (size_t)(m0 + (t >> 2)) * lda + (t & 3) * 8;
  int aR  = t >> 3;
  int ac4 = (t & 7) ^ (aR & 7);
  const float* afsrc = AF32 ? (const float*)Ap + (size_t)(m0 + aR) * lda + ac4 * 4
                            : (const float*)nullptr;

  f32x4 acc[4][4];
#pragma unroll
  for (int i = 0; i < 4; ++i)
#pragma unroll
    for (int j = 0; j < 4; ++j) acc[i][j] = (f32x4){0.f, 0.f, 0.f, 0.f};

  for (int k0 = 0; k0 < K; k0 += 32) {
    __syncthreads();
    if (AF32) {
#pragma unroll
      for (int r = 0; r < 4; ++r)
        gl_lds16(afsrc + k0 + (size_t)r * 32 * lda, (char*)AsF + r * 4096 + w * 1024);
    } else {
#pragma unroll
      for (int r = 0; r < 2; ++r)
        gl_lds16(ahsrc + k0 + (size_t)r * 64 * lda, (char*)AsH + r * 4096 + w * 1024);
    }
#pragma unroll
    for (int r = 0; r < 2; ++r)
      gl_lds16(bsrc + k0 + (size_t)r * 64 * K, (char*)Bs + r * 4096 + w * 1024);
    __syncthreads();

    s16x8 af[4], bf[4];
#pragma unroll
    for (int i = 0; i < 4; ++i) {
      int row = wm * 64 + i * 16 + l16;
      if (AF32) {
        int x = row & 7;
        const f32x4 lo = *(const f32x4*)(AsF + (size_t)(row * 8 + ((quad * 2) ^ x)) * 4);
        const f32x4 hi = *(const f32x4*)(AsF + (size_t)(row * 8 + ((quad * 2 + 1) ^ x)) * 4);
        s16x8 a;
        a[0] = f2bf(lo[0]); a[1] = f2bf(lo[1]); a[2] = f2bf(lo[2]); a[3] = f2bf(lo[3]);
        a[4] = f2bf(hi[0]); a[5] = f2bf(hi[1]); a[6] = f2bf(hi[2]); a[7] = f2bf(hi[3]);
        af[i] = a;
      } else {
        af[i] = *(const s16x8*)(AsH + row * 32 + quad * 8);
      }
      bf[i] = *(const s16x8*)(Bs + (wn * 64 + i * 16 + l16) * 32 + quad * 8);
    }
#pragma unroll
    for (int i = 0; i < 4; ++i)
#pragma unroll
      for (int j = 0; j < 4; ++j)
        acc[i][j] = __builtin_amdgcn_mfma_f32_16x16x32_bf16(af[i], bf[j], acc[i][j], 0, 0, 0);
  }

#pragma unroll
  for (int i = 0; i < 4; ++i)
#pragma unroll
    for (int j = 0; j < 4; ++j)
#pragma unroll
      for (int rr = 0; rr < 4; ++rr) {
        size_t row = m0 + wm * 64 + i * 16 + quad * 4 + rr;
        size_t col = n0 + wn * 64 + j * 16 + l16;
        if (OUTF32) ((float*)Cp)[row * ldc + col] = acc[i][j][rr];
        else        ((short*)Cp)[row * ldc + col] = f2bf(acc[i][j][rr]);
      }
}

// In-place 64x64 transpose of each V chunk: V[tok][d] -> V^T[d][tok] within the
// (b, h, chunk-of-64-tokens) block of the qkv V region.
__global__ __launch_bounds__(256)
void vtrans(short* __restrict__ qkv) {
  int x = blockIdx.x;                 // 1024 = c(32) | h(16) | b(2)
  int c = x & 31, h = (x >> 5) & 15, b = x >> 9;
  int t = threadIdx.x, wave = t >> 6, lane = t & 63;
  __shared__ __align__(16) short Ls[64][64];   // [tok][d], 8 KB
  size_t row0 = (size_t)(b * 2048 + c * 64);
  size_t vcol = 2048 + h * 64;
#pragma unroll
  for (int r = 0; r < 2; ++r) {
    int reg = wave * 2 + r;
    const short* src = qkv + (row0 + reg * 8 + (lane >> 3)) * 3072 + vcol + (lane & 7) * 8;
    gl_lds16(src, (char*)Ls + reg * 1024);
  }
  __syncthreads();
  int d = t & 63;
#pragma unroll
  for (int r = 0; r < 2; ++r) {
    int tok8 = r * 4 + (t >> 6);
    s16x8 p;
#pragma unroll
    for (int j = 0; j < 8; ++j) p[j] = Ls[tok8 * 8 + j][d];
    *(s16x8*)(qkv + (row0 + d) * 3072 + vcol + tok8 * 8) = p;
  }
}

// Flash attention, causal, transposed-softmax, double-buffered gl_lds staging.
// Requires vtrans() first (V region holds per-chunk V^T). Output in-place into Q region.
__global__ __launch_bounds__(256)
void attn(short* __restrict__ qkv) {
  const int L = 2048, E3 = 3072, EO = 1024;
  int bh = blockIdx.y, b = bh >> 4, h = bh & 15;
  int q0 = (int)(gridDim.x - 1 - blockIdx.x) * 64;   // heavy blocks first
  int t = threadIdx.x;
  int wave = t >> 6, lane = t & 63;
  int l16 = lane & 15, quad = lane >> 4;
  int qw = q0 + wave * 16;
  const float SENT = -3.0e38f;
  const float SC = 0.125f * LOG2E;

  __shared__ __align__(16) short Ks[2][2][64][32];  // [buf][dim chunk][key][dim%32] 16 KB
  __shared__ __align__(16) short Vt[2][2][64][32];  // [buf][key chunk][dim][key%32] 16 KB
  __shared__ __align__(16) short Pw[4][16][72];     // per-wave P^T [q][64 keys+pad] 9 KB

  int rowbase = b * L;
  const short* qp = qkv + (size_t)(rowbase + qw + l16) * E3 + h * 64 + quad * 8;
  s16x8 qf[2];
#pragma unroll
  for (int c = 0; c < 2; ++c) {
    s16x8 raw = *(const s16x8*)(qp + c * 32);
#pragma unroll
    for (int j = 0; j < 8; ++j) {
      union { float f; int i; } u; u.i = ((int)(unsigned short)raw[j]) << 16;
      raw[j] = f2bf(u.f * SC);
    }
    qf[c] = raw;
  }

  const short* ksrc = qkv + (size_t)(rowbase + wave * 16 + (lane >> 2)) * E3 + EO
                      + h * 64 + (lane & 3) * 8;
  const short* vsrc = qkv + (size_t)(rowbase + wave * 16 + (lane >> 2)) * E3 + 2 * EO
                      + h * 64 + (lane & 3) * 8;

  float m_s = SENT, l_s = 0.f;
  f32x4 o[4];
#pragma unroll
  for (int j = 0; j < 4; ++j) o[j] = (f32x4){0.f, 0.f, 0.f, 0.f};

  int nkb = q0 / 64 + 1;

  // prologue: stage tile 0 into buf 0
  gl_lds16(ksrc,      (char*)Ks + wave * 1024);
  gl_lds16(ksrc + 32, (char*)Ks + 4096 + wave * 1024);
  gl_lds16(vsrc,      (char*)Vt + wave * 1024);
  gl_lds16(vsrc + 32, (char*)Vt + 4096 + wave * 1024);

  for (int kb = 0; kb < nkb; ++kb) {
    int cur = kb & 1;
    __syncthreads();   // vmcnt drained: buf[cur] visible; buf[cur^1] free
    if (kb + 1 < nkb) {   // prefetch next tile, in flight across compute
      size_t koff = (size_t)((kb + 1) * 64) * E3;
      int nb = cur ^ 1;
      gl_lds16(ksrc + koff,      (char*)Ks + nb * 8192 + wave * 1024);
      gl_lds16(ksrc + koff + 32, (char*)Ks + nb * 8192 + 4096 + wave * 1024);
      gl_lds16(vsrc + koff,      (char*)Vt + nb * 8192 + wave * 1024);
      gl_lds16(vsrc + koff + 32, (char*)Vt + nb * 8192 + 4096 + wave * 1024);
    }

    int mtile = (qw - kb * 64) >> 4;   // >=4: all subtiles full

    f32x4 sf[4];
#pragma unroll
    for (int st = 0; st < 4; ++st) {
      if (st <= mtile) {
        s16x8 kf0 = *(const s16x8*)(&Ks[cur][0][st * 16 + l16][quad * 8]);
        s16x8 kf1 = *(const s16x8*)(&Ks[cur][1][st * 16 + l16][quad * 8]);
        f32x4 tt = (f32x4){0.f, 0.f, 0.f, 0.f};
        tt = __builtin_amdgcn_mfma_f32_16x16x32_bf16(kf0, qf[0], tt, 0, 0, 0);
        tt = __builtin_amdgcn_mfma_f32_16x16x32_bf16(kf1, qf[1], tt, 0, 0, 0);
        sf[st] = tt;
      }
    }
    if (mtile < 4) {
#pragma unroll
      for (int st = 0; st < 4; ++st) {
        if (st == mtile) {
#pragma unroll
          for (int r = 0; r < 4; ++r)
            if (quad * 4 + r > l16) sf[st][r] = SENT;
        } else if (st > mtile) {
          sf[st] = (f32x4){SENT, SENT, SENT, SENT};
        }
      }
    }

    // online softmax: in-register reduce + 2 shfl
    float rx = SENT;
#pragma unroll
    for (int st = 0; st < 4; ++st)
#pragma unroll
      for (int r = 0; r < 4; ++r) rx = fmaxf(rx, sf[st][r]);
    rx = fmaxf(rx, __shfl_xor(rx, 16));
    rx = fmaxf(rx, __shfl_xor(rx, 32));
    float mn = fmaxf(m_s, rx);
    float alpha = exp2f(m_s - mn);
    float rs = 0.f;
#pragma unroll
    for (int st = 0; st < 4; ++st)
#pragma unroll
      for (int r = 0; r < 4; ++r) {
        float p = exp2f(sf[st][r] - mn);
        sf[st][r] = p; rs += p;
      }
    rs += __shfl_xor(rs, 16);
    rs += __shfl_xor(rs, 32);
    l_s = l_s * alpha + rs;
    m_s = mn;
#pragma unroll
    for (int j = 0; j < 4; ++j)
#pragma unroll
      for (int r = 0; r < 4; ++r) o[j][r] *= alpha;

    // P^T -> per-wave LDS (b64 per subtile), read back as PV B-frags
#pragma unroll
    for (int st = 0; st < 4; ++st) {
      s16x4 pb;
#pragma unroll
      for (int r = 0; r < 4; ++r) pb[r] = f2bf(sf[st][r]);
      *(s16x4*)(&Pw[wave][l16][st * 16 + quad * 4]) = pb;
    }
    asm volatile("s_waitcnt lgkmcnt(0)" ::: "memory");
#pragma unroll
    for (int kc = 0; kc < 2; ++kc) {
      s16x8 pf = *(const s16x8*)(&Pw[wave][l16][kc * 32 + quad * 8]);
#pragma unroll
      for (int j = 0; j < 4; ++j) {
        s16x8 vf = *(const s16x8*)(&Vt[cur][kc][j * 16 + l16][quad * 8]);
        o[j] = __builtin_amdgcn_mfma_f32_16x16x32_bf16(vf, pf, o[j], 0, 0, 0);
      }
    }
  }

  // epilogue: O^T -> out rows (q = l16), b64 stores into own Q region
  float inv = 1.f / l_s;
  size_t obase = (size_t)(rowbase + qw + l16) * E3 + h * 64;
#pragma unroll
  for (int j = 0; j < 4; ++j) {
    s16x4 ob;
#pragma unroll
    for (int r = 0; r < 4; ++r) ob[r] = f2bf(o[j][r] * inv);
    *(s16x4*)(qkv + obase + j * 16 + quad * 4) = ob;
  }
}

extern "C" void kernel_launch(void* const* d_in, const int* in_sizes, int n_in,
                              void* d_out, int out_size, void* d_ws, size_t ws_size,
                              hipStream_t stream) {
  const float* net_in = (const float*)d_in[0];   // [4096,1024] fp32
  const float* W_qkv  = (const float*)d_in[1];   // [3072,1024] fp32
  const float* W_out  = (const float*)d_in[2];   // [1024,1024] fp32

  bool big = ws_size >= (size_t)40 * 1024 * 1024;   // room for a bf16 copy of net_in?
  char* p = (char*)d_ws;
  short* netb  = nullptr;
  if (big) { netb = (short*)p; p += (size_t)4096 * 1024 * 2; }   // 8 MB
  short* Wqkvb = (short*)p;  p += (size_t)3072 * 1024 * 2;       // 6 MB
  short* Woutb = (short*)p;  p += (size_t)1024 * 1024 * 2;       // 2 MB
  short* qkv   = (short*)p;                                       // 24 MB

  cvt_f32_bf16<<<3072, 256, 0, stream>>>(W_qkv, Wqkvb, 3072 * 1024 / 4);
  cvt_f32_bf16<<<1024, 256, 0, stream>>>(W_out, Woutb, 1024 * 1024 / 4);

  if (big) {
    cvt_f32_bf16<<<4096, 256, 0, stream>>>(net_in, netb, 4096 * 1024 / 4);
    gemm128<0, 0><<<dim3(32, 24), 256, 0, stream>>>(netb, 1024, Wqkvb, qkv, 3072, 1024);
  } else {
    gemm128<1, 0><<<dim3(32, 24), 256, 0, stream>>>(net_in, 1024, Wqkvb, qkv, 3072, 1024);
  }
  vtrans<<<1024, 256, 0, stream>>>(qkv);
  attn<<<dim3(32, 32), 256, 0, stream>>>(qkv);
  gemm128<0, 1><<<dim3(32, 8), 256, 0, stream>>>(qkv, 3072, Woutb, d_out, 1024, 1024);
}

// Round 8
// 238.272 us; speedup vs baseline: 3.6865x; 1.0920x over previous
//
#include <hip/hip_runtime.h>
#include <hip/hip_bf16.h>

// Dims fixed by the problem: B=2, L=2048, H=16, D=64, E=1024.
// MEASURED: inputs fp32, d_out fp32; bf16 internal compute absmax 0.0156 vs thr 0.0766.
// R6 BUG (fixed): Pw stride must be >=64 shorts (64-key P^T rows); 40 overflowed.
// R7 FINDING: CU classes (linear block id mod 256) fixed x -> 32x per-CU work imbalance.
//             Fix: q-block index = 31 - ((x+y)&31)  (bijective per y, spreads work per class).
#define LOG2E 1.44269504088896340736f

typedef __attribute__((ext_vector_type(8))) short s16x8;   // 8 x bf16 MFMA operand
typedef __attribute__((ext_vector_type(4))) short s16x4;
typedef __attribute__((ext_vector_type(4))) float f32x4;   // MFMA accumulator

__device__ inline short f2bf(float f) {
  __hip_bfloat16 h = __float2bfloat16(f);
  union { __hip_bfloat16 h; short s; } u; u.h = h; return u.s;
}

// async global->LDS, 16B per lane. LDS placement is wave-uniform base + lane*16.
__device__ inline void gl_lds16(const void* g, void* l) {
  __builtin_amdgcn_global_load_lds(
      (const __attribute__((address_space(1))) void*)g,
      (__attribute__((address_space(3))) void*)l, 16, 0, 0);
}

__global__ __launch_bounds__(256)
void cvt_f32_bf16(const float* __restrict__ src, short* __restrict__ dst, int n4) {
  int i = blockIdx.x * 256 + threadIdx.x;
  if (i < n4) {
    f32x4 v = ((const f32x4*)src)[i];
    s16x4 o;
    o[0] = f2bf(v[0]); o[1] = f2bf(v[1]); o[2] = f2bf(v[2]); o[3] = f2bf(v[3]);
    ((s16x4*)dst)[i] = o;
  }
}

// C[M,N] = A[M,K] @ B[N,K]^T.  m97-style 128x128 tile, BK=32, 4 waves (2x2), acc[4][4].
template<int AF32, int OUTF32>
__global__ __launch_bounds__(256)
void gemm128(const void* __restrict__ Ap, int lda,
             const short* __restrict__ B,
             void* __restrict__ Cp, int ldc, int K) {
  int m0 = blockIdx.x * 128;
  int n0 = blockIdx.y * 128;
  int t = threadIdx.x;
  int w = t >> 6, lane = t & 63;
  int l16 = lane & 15, quad = lane >> 4;
  int wm = w >> 1, wn = w & 1;

  __shared__ __align__(16) short Bs[128 * 32];                    // 8 KB
  __shared__ __align__(16) short AsH[AF32 ? 1 : 128 * 32];        // 8 KB (bf16 A)
  __shared__ __align__(16) float AsF[AF32 ? 128 * 32 : 1];        // 16 KB (fp32 A)

  const short* bsrc = B + (size_t)(n0 + (t >> 2)) * K + (t & 3) * 8;
  const short* ahsrc = AF32 ? (const short*)nullptr
                            : (const short*)Ap + (size_t)(m0 + (t >> 2)) * lda + (t & 3) * 8;
  int aR  = t >> 3;
  int ac4 = (t & 7) ^ (aR & 7);
  const float* afsrc = AF32 ? (const float*)Ap + (size_t)(m0 + aR) * lda + ac4 * 4
                            : (const float*)nullptr;

  f32x4 acc[4][4];
#pragma unroll
  for (int i = 0; i < 4; ++i)
#pragma unroll
    for (int j = 0; j < 4; ++j) acc[i][j] = (f32x4){0.f, 0.f, 0.f, 0.f};

  for (int k0 = 0; k0 < K; k0 += 32) {
    __syncthreads();
    if (AF32) {
#pragma unroll
      for (int r = 0; r < 4; ++r)
        gl_lds16(afsrc + k0 + (size_t)r * 32 * lda, (char*)AsF + r * 4096 + w * 1024);
    } else {
#pragma unroll
      for (int r = 0; r < 2; ++r)
        gl_lds16(ahsrc + k0 + (size_t)r * 64 * lda, (char*)AsH + r * 4096 + w * 1024);
    }
#pragma unroll
    for (int r = 0; r < 2; ++r)
      gl_lds16(bsrc + k0 + (size_t)r * 64 * K, (char*)Bs + r * 4096 + w * 1024);
    __syncthreads();

    s16x8 af[4], bf[4];
#pragma unroll
    for (int i = 0; i < 4; ++i) {
      int row = wm * 64 + i * 16 + l16;
      if (AF32) {
        int x = row & 7;
        const f32x4 lo = *(const f32x4*)(AsF + (size_t)(row * 8 + ((quad * 2) ^ x)) * 4);
        const f32x4 hi = *(const f32x4*)(AsF + (size_t)(row * 8 + ((quad * 2 + 1) ^ x)) * 4);
        s16x8 a;
        a[0] = f2bf(lo[0]); a[1] = f2bf(lo[1]); a[2] = f2bf(lo[2]); a[3] = f2bf(lo[3]);
        a[4] = f2bf(hi[0]); a[5] = f2bf(hi[1]); a[6] = f2bf(hi[2]); a[7] = f2bf(hi[3]);
        af[i] = a;
      } else {
        af[i] = *(const s16x8*)(AsH + row * 32 + quad * 8);
      }
      bf[i] = *(const s16x8*)(Bs + (wn * 64 + i * 16 + l16) * 32 + quad * 8);
    }
#pragma unroll
    for (int i = 0; i < 4; ++i)
#pragma unroll
      for (int j = 0; j < 4; ++j)
        acc[i][j] = __builtin_amdgcn_mfma_f32_16x16x32_bf16(af[i], bf[j], acc[i][j], 0, 0, 0);
  }

#pragma unroll
  for (int i = 0; i < 4; ++i)
#pragma unroll
    for (int j = 0; j < 4; ++j)
#pragma unroll
      for (int rr = 0; rr < 4; ++rr) {
        size_t row = m0 + wm * 64 + i * 16 + quad * 4 + rr;
        size_t col = n0 + wn * 64 + j * 16 + l16;
        if (OUTF32) ((float*)Cp)[row * ldc + col] = acc[i][j][rr];
        else        ((short*)Cp)[row * ldc + col] = f2bf(acc[i][j][rr]);
      }
}

// In-place 64x64 transpose of each V chunk: V[tok][d] -> V^T[d][tok] within the
// (b, h, chunk-of-64-tokens) block of the qkv V region.
__global__ __launch_bounds__(256)
void vtrans(short* __restrict__ qkv) {
  int x = blockIdx.x;                 // 1024 = c(32) | h(16) | b(2)
  int c = x & 31, h = (x >> 5) & 15, b = x >> 9;
  int t = threadIdx.x, wave = t >> 6, lane = t & 63;
  __shared__ __align__(16) short Ls[64][64];   // [tok][d], 8 KB
  size_t row0 = (size_t)(b * 2048 + c * 64);
  size_t vcol = 2048 + h * 64;
#pragma unroll
  for (int r = 0; r < 2; ++r) {
    int reg = wave * 2 + r;
    const short* src = qkv + (row0 + reg * 8 + (lane >> 3)) * 3072 + vcol + (lane & 7) * 8;
    gl_lds16(src, (char*)Ls + reg * 1024);
  }
  __syncthreads();
  int d = t & 63;
#pragma unroll
  for (int r = 0; r < 2; ++r) {
    int tok8 = r * 4 + (t >> 6);
    s16x8 p;
#pragma unroll
    for (int j = 0; j < 8; ++j) p[j] = Ls[tok8 * 8 + j][d];
    *(s16x8*)(qkv + (row0 + d) * 3072 + vcol + tok8 * 8) = p;
  }
}

// Flash attention, causal, transposed-softmax, double-buffered gl_lds staging.
// Requires vtrans() first (V region holds per-chunk V^T). Output in-place into Q region.
__global__ __launch_bounds__(256)
void attn(short* __restrict__ qkv) {
  const int L = 2048, E3 = 3072, EO = 1024;
  int bh = blockIdx.y, b = bh >> 4, h = bh & 15;
  // Work-balanced swizzle: q-block index varies along BOTH grid axes so every
  // stride-256 dispatch class (one CU's share) gets a mixed light/heavy set.
  int qidx = 31 - (int)((blockIdx.x + blockIdx.y) & 31);
  int q0 = qidx * 64;
  int t = threadIdx.x;
  int wave = t >> 6, lane = t & 63;
  int l16 = lane & 15, quad = lane >> 4;
  int qw = q0 + wave * 16;
  const float SENT = -3.0e38f;
  const float SC = 0.125f * LOG2E;

  __shared__ __align__(16) short Ks[2][2][64][32];  // [buf][dim chunk][key][dim%32] 16 KB
  __shared__ __align__(16) short Vt[2][2][64][32];  // [buf][key chunk][dim][key%32] 16 KB
  __shared__ __align__(16) short Pw[4][16][72];     // per-wave P^T [q][64 keys+pad] 9 KB

  int rowbase = b * L;
  const short* qp = qkv + (size_t)(rowbase + qw + l16) * E3 + h * 64 + quad * 8;
  s16x8 qf[2];
#pragma unroll
  for (int c = 0; c < 2; ++c) {
    s16x8 raw = *(const s16x8*)(qp + c * 32);
#pragma unroll
    for (int j = 0; j < 8; ++j) {
      union { float f; int i; } u; u.i = ((int)(unsigned short)raw[j]) << 16;
      raw[j] = f2bf(u.f * SC);
    }
    qf[c] = raw;
  }

  const short* ksrc = qkv + (size_t)(rowbase + wave * 16 + (lane >> 2)) * E3 + EO
                      + h * 64 + (lane & 3) * 8;
  const short* vsrc = qkv + (size_t)(rowbase + wave * 16 + (lane >> 2)) * E3 + 2 * EO
                      + h * 64 + (lane & 3) * 8;

  float m_s = SENT, l_s = 0.f;
  f32x4 o[4];
#pragma unroll
  for (int j = 0; j < 4; ++j) o[j] = (f32x4){0.f, 0.f, 0.f, 0.f};

  int nkb = q0 / 64 + 1;

  // prologue: stage tile 0 into buf 0
  gl_lds16(ksrc,      (char*)Ks + wave * 1024);
  gl_lds16(ksrc + 32, (char*)Ks + 4096 + wave * 1024);
  gl_lds16(vsrc,      (char*)Vt + wave * 1024);
  gl_lds16(vsrc + 32, (char*)Vt + 4096 + wave * 1024);

  for (int kb = 0; kb < nkb; ++kb) {
    int cur = kb & 1;
    __syncthreads();   // vmcnt drained: buf[cur] visible; buf[cur^1] free
    if (kb + 1 < nkb) {   // prefetch next tile, in flight across compute
      size_t koff = (size_t)((kb + 1) * 64) * E3;
      int nb = cur ^ 1;
      gl_lds16(ksrc + koff,      (char*)Ks + nb * 8192 + wave * 1024);
      gl_lds16(ksrc + koff + 32, (char*)Ks + nb * 8192 + 4096 + wave * 1024);
      gl_lds16(vsrc + koff,      (char*)Vt + nb * 8192 + wave * 1024);
      gl_lds16(vsrc + koff + 32, (char*)Vt + nb * 8192 + 4096 + wave * 1024);
    }

    int mtile = (qw - kb * 64) >> 4;   // >=4: all subtiles full

    f32x4 sf[4];
#pragma unroll
    for (int st = 0; st < 4; ++st) {
      if (st <= mtile) {
        s16x8 kf0 = *(const s16x8*)(&Ks[cur][0][st * 16 + l16][quad * 8]);
        s16x8 kf1 = *(const s16x8*)(&Ks[cur][1][st * 16 + l16][quad * 8]);
        f32x4 tt = (f32x4){0.f, 0.f, 0.f, 0.f};
        tt = __builtin_amdgcn_mfma_f32_16x16x32_bf16(kf0, qf[0], tt, 0, 0, 0);
        tt = __builtin_amdgcn_mfma_f32_16x16x32_bf16(kf1, qf[1], tt, 0, 0, 0);
        sf[st] = tt;
      }
    }
    if (mtile < 4) {
#pragma unroll
      for (int st = 0; st < 4; ++st) {
        if (st == mtile) {
#pragma unroll
          for (int r = 0; r < 4; ++r)
            if (quad * 4 + r > l16) sf[st][r] = SENT;
        } else if (st > mtile) {
          sf[st] = (f32x4){SENT, SENT, SENT, SENT};
        }
      }
    }

    // online softmax: in-register reduce + 2 shfl
    float rx = SENT;
#pragma unroll
    for (int st = 0; st < 4; ++st)
#pragma unroll
      for (int r = 0; r < 4; ++r) rx = fmaxf(rx, sf[st][r]);
    rx = fmaxf(rx, __shfl_xor(rx, 16));
    rx = fmaxf(rx, __shfl_xor(rx, 32));
    float mn = fmaxf(m_s, rx);
    float alpha = exp2f(m_s - mn);
    float rs = 0.f;
#pragma unroll
    for (int st = 0; st < 4; ++st)
#pragma unroll
      for (int r = 0; r < 4; ++r) {
        float p = exp2f(sf[st][r] - mn);
        sf[st][r] = p; rs += p;
      }
    rs += __shfl_xor(rs, 16);
    rs += __shfl_xor(rs, 32);
    l_s = l_s * alpha + rs;
    m_s = mn;
#pragma unroll
    for (int j = 0; j < 4; ++j)
#pragma unroll
      for (int r = 0; r < 4; ++r) o[j][r] *= alpha;

    // P^T -> per-wave LDS (b64 per subtile), read back as PV B-frags
#pragma unroll
    for (int st = 0; st < 4; ++st) {
      s16x4 pb;
#pragma unroll
      for (int r = 0; r < 4; ++r) pb[r] = f2bf(sf[st][r]);
      *(s16x4*)(&Pw[wave][l16][st * 16 + quad * 4]) = pb;
    }
    asm volatile("s_waitcnt lgkmcnt(0)" ::: "memory");
#pragma unroll
    for (int kc = 0; kc < 2; ++kc) {
      s16x8 pf = *(const s16x8*)(&Pw[wave][l16][kc * 32 + quad * 8]);
#pragma unroll
      for (int j = 0; j < 4; ++j) {
        s16x8 vf = *(const s16x8*)(&Vt[cur][kc][j * 16 + l16][quad * 8]);
        o[j] = __builtin_amdgcn_mfma_f32_16x16x32_bf16(vf, pf, o[j], 0, 0, 0);
      }
    }
  }

  // epilogue: O^T -> out rows (q = l16), b64 stores into own Q region
  float inv = 1.f / l_s;
  size_t obase = (size_t)(rowbase + qw + l16) * E3 + h * 64;
#pragma unroll
  for (int j = 0; j < 4; ++j) {
    s16x4 ob;
#pragma unroll
    for (int r = 0; r < 4; ++r) ob[r] = f2bf(o[j][r] * inv);
    *(s16x4*)(qkv + obase + j * 16 + quad * 4) = ob;
  }
}

extern "C" void kernel_launch(void* const* d_in, const int* in_sizes, int n_in,
                              void* d_out, int out_size, void* d_ws, size_t ws_size,
                              hipStream_t stream) {
  const float* net_in = (const float*)d_in[0];   // [4096,1024] fp32
  const float* W_qkv  = (const float*)d_in[1];   // [3072,1024] fp32
  const float* W_out  = (const float*)d_in[2];   // [1024,1024] fp32

  bool big = ws_size >= (size_t)40 * 1024 * 1024;   // room for a bf16 copy of net_in?
  char* p = (char*)d_ws;
  short* netb  = nullptr;
  if (big) { netb = (short*)p; p += (size_t)4096 * 1024 * 2; }   // 8 MB
  short* Wqkvb = (short*)p;  p += (size_t)3072 * 1024 * 2;       // 6 MB
  short* Woutb = (short*)p;  p += (size_t)1024 * 1024 * 2;       // 2 MB
  short* qkv   = (short*)p;                                       // 24 MB

  cvt_f32_bf16<<<3072, 256, 0, stream>>>(W_qkv, Wqkvb, 3072 * 1024 / 4);
  cvt_f32_bf16<<<1024, 256, 0, stream>>>(W_out, Woutb, 1024 * 1024 / 4);

  if (big) {
    cvt_f32_bf16<<<4096, 256, 0, stream>>>(net_in, netb, 4096 * 1024 / 4);
    gemm128<0, 0><<<dim3(32, 24), 256, 0, stream>>>(netb, 1024, Wqkvb, qkv, 3072, 1024);
  } else {
    gemm128<1, 0><<<dim3(32, 24), 256, 0, stream>>>(net_in, 1024, Wqkvb, qkv, 3072, 1024);
  }
  vtrans<<<1024, 256, 0, stream>>>(qkv);
  attn<<<dim3(32, 32), 256, 0, stream>>>(qkv);
  gemm128<0, 1><<<dim3(32, 8), 256, 0, stream>>>(qkv, 3072, Woutb, d_out, 1024, 1024);
}